// Round 1
// baseline (1489.456 us; speedup 1.0000x reference)
//
#include <hip/hip_runtime.h>
#include <hip/hip_bf16.h>

#define NH 8
#define DH 64
#define SL 512
#define BHT 64   // B * NH

typedef __bf16 bf16x8 __attribute__((ext_vector_type(8)));
typedef float f32x16 __attribute__((ext_vector_type(16)));
typedef unsigned short us8 __attribute__((ext_vector_type(8)));
typedef unsigned int u32;

#define MFMA(a, b, c) __builtin_amdgcn_mfma_f32_32x32x16_bf16(a, b, c, 0, 0, 0)
#define ZERO16 {0.f,0.f,0.f,0.f,0.f,0.f,0.f,0.f,0.f,0.f,0.f,0.f,0.f,0.f,0.f,0.f}

// ---------- dtype-detect: is the input buffer bf16 or fp32? ----------
__global__ void detect_dtype_kernel(const unsigned short* __restrict__ q, int* __restrict__ flag) {
    int t = threadIdx.x;
    unsigned int u = (unsigned int)q[t];
    float f = __uint_as_float(u << 16);
    bool big = !(fabsf(f) <= 1e4f);   // true for huge OR NaN
    unsigned long long vote = __ballot(big);
    __shared__ int any;
    if (t == 0) any = 0;
    __syncthreads();
    if (vote != 0ull && (t & 63) == 0) atomicOr(&any, 1);
    __syncthreads();
    if (t == 0) *flag = any;          // 1 => fp32 data, 0 => bf16 data
}

// ---------- load/store helpers (fallback path) ----------
__device__ __forceinline__ float ldv(const __hip_bfloat16* p) { return __bfloat162float(*p); }
__device__ __forceinline__ float ldv(const float* p) { return *p; }
__device__ __forceinline__ void stv(__hip_bfloat16* p, float v) { *p = __float2bfloat16(v); }
__device__ __forceinline__ void stv(float* p, float v) { *p = v; }

// ---------- transpose: qkv [bh][3*64][512] -> q' , k'  as [bh][512][64] (bf16, MODE 0 only) ----------
__global__ __launch_bounds__(256) void transpose_qk_kernel(
    const __hip_bfloat16* __restrict__ qkv,
    __hip_bfloat16* __restrict__ outq,
    __hip_bfloat16* __restrict__ outk,
    const int* __restrict__ flag)
{
    if (*flag != 0) return;
    const int bid = blockIdx.x;            // 64 bh * 2 sel * 8 ltile = 1024
    const int lt  = bid & 7;
    const int sel = (bid >> 3) & 1;
    const int bh  = bid >> 4;
    const unsigned short* src = (const unsigned short*)qkv
        + (size_t)bh * (3 * DH * SL) + (size_t)sel * (DH * SL) + lt * 64;
    unsigned short* dst = (unsigned short*)(sel ? outk : outq)
        + ((size_t)bh * SL + lt * 64) * DH;
    __shared__ unsigned short tile[64][72];   // pad 72 -> 16B-aligned rows
    const int t = threadIdx.x;
    {
        const int d = t >> 2, c = (t & 3) * 16;
        us8 a = *(const us8*)(src + (size_t)d * SL + c);
        us8 b = *(const us8*)(src + (size_t)d * SL + c + 8);
#pragma unroll
        for (int i = 0; i < 8; ++i) { tile[c + i][d] = a[i]; tile[c + 8 + i][d] = b[i]; }
    }
    __syncthreads();
    {
        const int l = t >> 2, p = (t & 3) * 16;
        us8 a = *(const us8*)&tile[l][p];
        us8 b = *(const us8*)&tile[l][p + 8];
        *(us8*)(dst + (size_t)l * DH + p)     = a;
        *(us8*)(dst + (size_t)l * DH + p + 8) = b;
    }
}

// ---------- fused flash attention w/ relative logits, bf16 MFMA (MODE 0) ----------
// Per block: one (bh, 64-row l-tile). 4 waves: wave = (slab = wid&1 [32 rows], mh = wid>>1 [m-half]).
// S^T tile = mfma(A=K'rows, B=Q'rows)  -> lane holds column l'=lane&31, rows m' in regs.
// rel rect  = mfma(A=k_emb rows, B=Q') -> sheared add via padded-LDS bounce (j = m'-l'+31).
// PV as O^T = mfma(A=V^T rows (native layout), B=P^T (cvt_pk + shfl_xor(32) frags)).
__global__ __launch_bounds__(256, 2) void attn_flash_bf16(
    const __hip_bfloat16* __restrict__ qkv,     // for V (native [d][m])
    const __hip_bfloat16* __restrict__ k_emb,   // [H][1023][64] d-contiguous
    const __hip_bfloat16* __restrict__ qws,     // [bh][512][64]
    const __hip_bfloat16* __restrict__ kws,     // [bh][512][64]
    __hip_bfloat16* __restrict__ out,           // [bh][512][64]
    const int* __restrict__ flag)
{
    if (*flag != 0) return;
    const int bid = blockIdx.x;
    // XCD swizzle: 8 l-tiles of one bh land on one XCD (512 = 8*64, bijective)
    const int swz = (bid & 7) * 64 + (bid >> 3);
    const int bh = swz >> 3, lt = swz & 7;
    const int h  = bh & (NH - 1);
    const int t = threadIdx.x;
    const int wid = t >> 6, lane = t & 63;
    const int lo = lane & 31, hi = lane >> 5;
    const int slab = wid & 1, mh = wid >> 1;
    const int l0w = lt * 64 + slab * 32;

    __shared__ float srect[4][64 * 34];   // per-wave rel rect (pad 34: conflict-free shear read)
    __shared__ float sstat[2][2][32];     // [slab][mx|sum][l']
    float* rect = srect[wid];

    // Q fragments for this wave's 32 rows (held in regs across the whole m-loop)
    const bf16x8* qrow = (const bf16x8*)(qws + ((size_t)bh * SL + l0w + lo) * DH);
    const bf16x8 qf[4] = { qrow[hi], qrow[2 + hi], qrow[4 + hi], qrow[6 + hi] };

    const bf16x8* kbase = (const bf16x8*)(kws + (size_t)bh * SL * DH);
    const bf16x8* ebase = (const bf16x8*)(k_emb + (size_t)h * (2 * SL - 1) * DH);
    const __hip_bfloat16* vflat = qkv + (size_t)bh * (3 * DH * SL) + (size_t)2 * DH * SL;
    const bf16x8* vb0 = (const bf16x8*)(vflat + (size_t)lo * SL);        // V^T rows d = lo
    const bf16x8* vb1 = (const bf16x8*)(vflat + (size_t)(32 + lo) * SL); // V^T rows d = 32+lo

    f32x16 o0 = ZERO16, o1 = ZERO16;      // O^T accum: d 0-31 / 32-63, col l' = lo
    float mx = -1e30f, sum = 0.f;

    for (int step = 0; step < 8; ++step) {
        const int m0 = mh * 256 + step * 32;
        const int rb = m0 - l0w + 480;                       // rect row base (>= 0 always)
        int r1row = rb + 32 + lo; if (r1row > 1022) r1row = 1022;  // row j=63 unused; clamp OOB
        const bf16x8* ep0 = ebase + (size_t)(rb + lo) * 8;
        const bf16x8* ep1 = ebase + (size_t)r1row * 8;
        const bf16x8* kp  = kbase + (size_t)(m0 + lo) * 8;

        f32x16 ra = ZERO16, rc = ZERO16, sacc = ZERO16;
#pragma unroll
        for (int ds = 0; ds < 4; ++ds) {
            bf16x8 e0 = ep0[2 * ds + hi];
            bf16x8 e1 = ep1[2 * ds + hi];
            bf16x8 kf = kp [2 * ds + hi];
            ra   = MFMA(e0, qf[ds], ra);     // rel rect rows j = 0..31
            rc   = MFMA(e1, qf[ds], rc);     // rel rect rows j = 32..63
            sacc = MFMA(kf, qf[ds], sacc);   // S^T tile
        }
        // V fragments for this m-tile (issued early; consumed after softmax)
        const int mu = (m0 >> 3) + hi;
        bf16x8 vf00 = vb0[mu], vf01 = vb0[mu + 2];
        bf16x8 vf10 = vb1[mu], vf11 = vb1[mu + 2];

        // rect -> LDS (write banks: 2-way max), then sheared gather into S
#pragma unroll
        for (int r = 0; r < 16; ++r) {
            const int j = (r & 3) + 8 * (r >> 2) + 4 * hi;
            rect[j * 34 + lo]        = ra[r];
            rect[(j + 32) * 34 + lo] = rc[r];
        }
        float s[16];
#pragma unroll
        for (int r = 0; r < 16; ++r) {
            const int mp = (r & 3) + 8 * (r >> 2) + 4 * hi;   // m' of this reg
            s[r] = sacc[r] + rect[(mp + 31 - lo) * 34 + lo];  // + rel^T[m'][l']
        }

        // ---- online softmax (per-lane column l'; merge hi-pair via shfl_xor 32) ----
        float tmx = s[0];
#pragma unroll
        for (int r = 1; r < 16; ++r) tmx = fmaxf(tmx, s[r]);
        tmx = fmaxf(tmx, __shfl_xor(tmx, 32, 64));
        const float nmx = fmaxf(mx, tmx);
        if (__any(nmx > mx)) {
            const float sc = __expf(mx - nmx);
#pragma unroll
            for (int r = 0; r < 16; ++r) { o0[r] *= sc; o1[r] *= sc; }
            sum *= sc;
            mx = nmx;
        }
        u32 pk[8], xk[8];
        float ps = 0.f;
#pragma unroll
        for (int q2 = 0; q2 < 8; ++q2) {
            union { __hip_bfloat162 b; u32 u; } cv;
            cv.b = __float22bfloat162_rn(make_float2(__expf(s[2 * q2] - mx),
                                                     __expf(s[2 * q2 + 1] - mx)));
            pk[q2] = cv.u;
            float2 g = __bfloat1622float2(cv.b);   // sum the *rounded* P for consistency
            ps += g.x + g.y;
        }
        sum += ps;
#pragma unroll
        for (int q2 = 0; q2 < 8; ++q2) xk[q2] = (u32)__shfl_xor((int)pk[q2], 32, 64);

        // P^T B-fragments (k = m within slice; swap middle quads with hi-partner)
        union { u32 u[4]; bf16x8 v; } pf0, pf1;
        if (hi == 0) {
            pf0.u[0] = pk[0]; pf0.u[1] = pk[1]; pf0.u[2] = xk[0]; pf0.u[3] = xk[1];
            pf1.u[0] = pk[4]; pf1.u[1] = pk[5]; pf1.u[2] = xk[4]; pf1.u[3] = xk[5];
        } else {
            pf0.u[0] = xk[2]; pf0.u[1] = xk[3]; pf0.u[2] = pk[2]; pf0.u[3] = pk[3];
            pf1.u[0] = xk[6]; pf1.u[1] = xk[7]; pf1.u[2] = pk[6]; pf1.u[3] = pk[7];
        }
        o0 = MFMA(vf00, pf0.v, o0);
        o0 = MFMA(vf01, pf1.v, o0);
        o1 = MFMA(vf10, pf0.v, o1);
        o1 = MFMA(vf11, pf1.v, o1);
    }

    // merge hi-pair partial sums (mx already identical across the pair)
    sum += __shfl_xor(sum, 32, 64);

    // ---- flash merge of the two m-halves (mh==1 publishes, mh==0 combines & stores) ----
    if (mh == 1) {
        if (hi == 0) { sstat[slab][0][lo] = mx; sstat[slab][1][lo] = sum; }
        float* ob = rect;   // reuse own rect region: [d][l'] pad 33 (conflict-free)
#pragma unroll
        for (int r = 0; r < 16; ++r) {
            const int d0 = (r & 3) + 8 * (r >> 2) + 4 * hi;
            ob[d0 * 33 + lo]        = o0[r];
            ob[(32 + d0) * 33 + lo] = o1[r];
        }
    }
    __syncthreads();
    if (mh == 0) {
        const float mx1 = sstat[slab][0][lo], s1 = sstat[slab][1][lo];
        const float nm = fmaxf(mx, mx1);
        const float a0 = __expf(mx - nm);
        const float a1 = __expf(mx1 - nm);
        const float inv = 1.f / (a0 * sum + a1 * s1);
        const float* ob = srect[wid + 2];
        unsigned short* orow = (unsigned short*)out + ((size_t)bh * SL + l0w + lo) * DH;
#pragma unroll
        for (int r = 0; r < 16; r += 2) {
            const int d0 = (r & 3) + 8 * (r >> 2) + 4 * hi;   // even; (r,r+1) -> (d0,d0+1)
            union { __hip_bfloat162 b; u32 u; } c0, c1;
            c0.b = __float22bfloat162_rn(make_float2(
                (a0 * o0[r]     + a1 * ob[d0 * 33 + lo]) * inv,
                (a0 * o0[r + 1] + a1 * ob[(d0 + 1) * 33 + lo]) * inv));
            *(u32*)(orow + d0) = c0.u;
            c1.b = __float22bfloat162_rn(make_float2(
                (a0 * o1[r]     + a1 * ob[(32 + d0) * 33 + lo]) * inv,
                (a0 * o1[r + 1] + a1 * ob[(32 + d0 + 1) * 33 + lo]) * inv));
            *(u32*)(orow + 32 + d0) = c1.u;
        }
    }
}

// ---------- fallback scalar path (fp32 MODE 1 always; bf16 MODE 0 only if ws too small) ----------
// grid 2048, 16 rows per block (small inert-dispatch cost when disabled by flag)
template <typename T, int MODE>
__global__ __launch_bounds__(256) void attn_rel_kernel(
    const T* __restrict__ qkv, const T* __restrict__ k_emb,
    T* __restrict__ out, const int* __restrict__ flag)
{
    if (*flag != MODE) return;
    const int t = threadIdx.x;
    __shared__ float s_q[DH];
    __shared__ float s_w[SL];
    __shared__ float s_red[24];
    __shared__ float s_part[256];

    for (int it = 0; it < 16; ++it) {
        const int bid = blockIdx.x * 16 + it;
        const int l   = bid & (SL - 1);
        const int bh  = bid >> 9;
        const int h   = bh & (NH - 1);
        const long base = (long)bh * (3 * DH) * SL;

        __syncthreads();
        if (t < DH) s_q[t] = ldv(&qkv[base + (long)t * SL + l]);
        __syncthreads();

        const T* kp = qkv + base + (long)DH * SL;
        const T* ke = k_emb + (long)h * (2 * SL - 1) * DH;
        float lg[2];
#pragma unroll
        for (int i = 0; i < 2; ++i) {
            const int m = t + i * 256;
            float acc = 0.f;
#pragma unroll 8
            for (int d = 0; d < DH; ++d)
                acc += s_q[d] * ldv(&kp[(long)d * SL + m]);
            const int r = m - l + (SL - 1);
            const T* kr = ke + (long)r * DH;
            float acc2 = 0.f;
#pragma unroll 8
            for (int d = 0; d < DH; ++d)
                acc2 += s_q[d] * ldv(&kr[d]);
            lg[i] = acc + acc2;
        }

        float mxv = fmaxf(lg[0], lg[1]);
        for (int off = 32; off > 0; off >>= 1)
            mxv = fmaxf(mxv, __shfl_down(mxv, off, 64));
        if ((t & 63) == 0) s_red[t >> 6] = mxv;
        __syncthreads();
        if (t == 0)
            s_red[8] = fmaxf(fmaxf(s_red[0], s_red[1]), fmaxf(s_red[2], s_red[3]));
        __syncthreads();
        mxv = s_red[8];

        const float e0 = expf(lg[0] - mxv);
        const float e1 = expf(lg[1] - mxv);
        s_w[t] = e0;
        s_w[t + 256] = e1;
        float sm = e0 + e1;
        for (int off = 32; off > 0; off >>= 1)
            sm += __shfl_down(sm, off, 64);
        if ((t & 63) == 0) s_red[16 + (t >> 6)] = sm;
        __syncthreads();
        const float inv = 1.0f / (s_red[16] + s_red[17] + s_red[18] + s_red[19]);

        const T* vp = qkv + base + (long)(2 * DH) * SL;
        const int g  = t >> 6;
        const int dd = t & 63;
        const T* vrow = vp + (long)dd * SL + g * 128;
        const float* wrow = s_w + g * 128;
        float acc = 0.f;
#pragma unroll 8
        for (int m = 0; m < 128; ++m)
            acc += wrow[m] * ldv(&vrow[m]);
        s_part[t] = acc;
        __syncthreads();
        if (t < 64) {
            float o = (s_part[t] + s_part[t + 64] + s_part[t + 128] + s_part[t + 192]) * inv;
            stv(&out[((long)bh * SL + l) * DH + t], o);
        }
    }
}

extern "C" void kernel_launch(void* const* d_in, const int* in_sizes, int n_in,
                              void* d_out, int out_size, void* d_ws, size_t ws_size,
                              hipStream_t stream) {
    (void)in_sizes; (void)n_in; (void)out_size;
    int* flag = (int*)d_ws;

    detect_dtype_kernel<<<1, 256, 0, stream>>>((const unsigned short*)d_in[0], flag);

    const size_t need = 1024 + (size_t)2 * BHT * SL * DH * sizeof(unsigned short); // ~8.4 MB
    if (ws_size >= need) {
        __hip_bfloat16* qws = (__hip_bfloat16*)((char*)d_ws + 512);
        __hip_bfloat16* kws = qws + (size_t)BHT * SL * DH;
        transpose_qk_kernel<<<BHT * 2 * 8, 256, 0, stream>>>(
            (const __hip_bfloat16*)d_in[0], qws, kws, flag);
        attn_flash_bf16<<<512, 256, 0, stream>>>(
            (const __hip_bfloat16*)d_in[0], (const __hip_bfloat16*)d_in[1],
            qws, kws, (__hip_bfloat16*)d_out, flag);
    } else {
        attn_rel_kernel<__hip_bfloat16, 0><<<2048, 256, 0, stream>>>(
            (const __hip_bfloat16*)d_in[0], (const __hip_bfloat16*)d_in[1],
            (__hip_bfloat16*)d_out, flag);
    }

    // fp32 interpretation (MODE 1) — self-disables via flag when data is bf16
    attn_rel_kernel<float, 1><<<2048, 256, 0, stream>>>(
        (const float*)d_in[0], (const float*)d_in[1], (float*)d_out, flag);
}

// Round 2
// 1487.852 us; speedup vs baseline: 1.0011x; 1.0011x over previous
//
#include <hip/hip_runtime.h>
#include <hip/hip_bf16.h>

#define NH 8
#define DH 64
#define SL 512

typedef __bf16 bf16x8 __attribute__((ext_vector_type(8)));
typedef float f32x16 __attribute__((ext_vector_type(16)));
typedef float f32x4 __attribute__((ext_vector_type(4)));
typedef unsigned short us8 __attribute__((ext_vector_type(8)));
typedef unsigned int u32;

#define MFMA(a, b, c) __builtin_amdgcn_mfma_f32_32x32x16_bf16(a, b, c, 0, 0, 0)
#define ZERO16 {0.f,0.f,0.f,0.f,0.f,0.f,0.f,0.f,0.f,0.f,0.f,0.f,0.f,0.f,0.f,0.f}

// ---------- dtype-detect: is the input buffer bf16 or fp32? ----------
__global__ void detect_dtype_kernel(const unsigned short* __restrict__ q, int* __restrict__ flag) {
    int t = threadIdx.x;
    unsigned int u = (unsigned int)q[t];
    float f = __uint_as_float(u << 16);
    bool big = !(fabsf(f) <= 1e4f);   // true for huge OR NaN
    unsigned long long vote = __ballot(big);
    __shared__ int any;
    if (t == 0) any = 0;
    __syncthreads();
    if (vote != 0ull && (t & 63) == 0) atomicOr(&any, 1);
    __syncthreads();
    if (t == 0) *flag = any;          // 1 => fp32 data, 0 => bf16 data
}

// ---------- load/store helpers (fallback path) ----------
__device__ __forceinline__ float ldv(const __hip_bfloat16* p) { return __bfloat162float(*p); }
__device__ __forceinline__ float ldv(const float* p) { return *p; }
__device__ __forceinline__ void stv(__hip_bfloat16* p, float v) { *p = __float2bfloat16(v); }
__device__ __forceinline__ void stv(float* p, float v) { *p = v; }

// ---------- fused flash attention w/ relative logits, bf16 MFMA (MODE 0) ----------
// One block per (bh, 64-row l-tile); NO global workspace (Q/K transposed in LDS).
// 4 waves: wave = (slab = wid&1 [which 32 l-rows], mh = wid>>1 [which 256-m half]).
// S^T tile = mfma(A=K rows, B=Q rows)  -> lane holds col l'=lane&31, rows m' in regs.
// rel rect  = mfma(A=k_emb rows, B=Q)  -> sheared add via XOR-swizzled LDS bounce.
// PV as O^T = mfma(A=V^T rows (native [d][m] layout), B=P^T via cvt_pk + shfl_xor(32)).
__global__ __launch_bounds__(256, 2) void attn_flash_bf16(
    const __hip_bfloat16* __restrict__ qkv,     // [bh][3*64][512]
    const __hip_bfloat16* __restrict__ k_emb,   // [H][1023][64] d-contiguous
    __hip_bfloat16* __restrict__ out,           // [bh][512][64] raw
    const int* __restrict__ flag)
{
    if (*flag != 0) return;
    const int bid = blockIdx.x;
    // XCD swizzle: XCD c gets bh in [8c,8c+8) entirely (K/V/k_emb L2-resident per XCD)
    const int swz = (bid & 7) * 64 + (bid >> 3);
    const int bh = swz >> 3, lt = swz & 7;
    const int h  = bh & (NH - 1);
    const int t = threadIdx.x;
    const int wid = t >> 6, lane = t & 63;
    const int lo = lane & 31, hi = lane >> 5;
    const int slab = wid & 1, mh = wid >> 1;
    const int l0w = lt * 64 + slab * 32;

    __shared__ unsigned short sq[64][72];           // Q tile [l][d], pad 72 (16B rows)
    __shared__ unsigned short sk[2][2][32][72];     // K tiles [buf][mh][m][d]
    __shared__ float srect[4][32 * 64];             // per-wave rel rect [l'][j], XOR-swizzled
    __shared__ float sstat[2][2][32];               // [slab][mx|sum][l']

    const unsigned short* qbase = (const unsigned short*)qkv + (size_t)bh * (3 * DH * SL);
    const unsigned short* kglob = qbase + (size_t)DH * SL;

    // ---- stage Q tile (transpose [d][l] -> [l][d]) ----
    {
        const int d = t >> 2, c = (t & 3) * 16;
        const unsigned short* src = qbase + (size_t)d * SL + lt * 64 + c;
        us8 a = *(const us8*)src;
        us8 b = *(const us8*)(src + 8);
#pragma unroll
        for (int i = 0; i < 8; ++i) { sq[c + i][d] = a[i]; sq[c + 8 + i][d] = b[i]; }
    }
    // ---- stage K tile for step 0 (each mh-pair stages its own tile) ----
    {
        const int tid2 = slab * 64 + lane;          // 0..127 within mh-pair
        const int d = tid2 >> 1, mo = (tid2 & 1) << 4;
        const unsigned short* src = kglob + (size_t)d * SL + mh * 256 + mo;
        us8 a = *(const us8*)src;
        us8 b = *(const us8*)(src + 8);
#pragma unroll
        for (int i = 0; i < 8; ++i) { sk[0][mh][mo + i][d] = a[i]; sk[0][mh][mo + 8 + i][d] = b[i]; }
    }
    __syncthreads();

    // Q fragments for this wave's 32 rows (regs for the whole m-loop)
    bf16x8 qf[4];
#pragma unroll
    for (int ds = 0; ds < 4; ++ds)
        qf[ds] = *(const bf16x8*)&sq[slab * 32 + lo][16 * ds + 8 * hi];

    const bf16x8* ebase = (const bf16x8*)(k_emb + (size_t)h * (2 * SL - 1) * DH);
    const unsigned short* vflat = qbase + (size_t)2 * DH * SL;
    const bf16x8* vb0 = (const bf16x8*)(vflat + (size_t)lo * SL);        // V^T rows d = lo
    const bf16x8* vb1 = (const bf16x8*)(vflat + (size_t)(32 + lo) * SL); // V^T rows d = 32+lo

    float* rect = srect[wid];
    float* rrow = rect + lo * 64;
    const int sw = (lo & 7) << 2;   // col XOR-swizzle (bits 2-4): conflict-free b128 writes

    f32x16 o0 = ZERO16, o1 = ZERO16;      // O^T accum: d 0-31 / 32-63, col l' = lo
    float mx = -1e30f, sum = 0.f;

    for (int step = 0; step < 8; ++step) {
        const int cur = step & 1;
        const int m0 = mh * 256 + step * 32;

        // prefetch-stage next K tile into buf cur^1 (issued early, lands before next barrier)
        if (step < 7) {
            const int tid2 = slab * 64 + lane;
            const int d = tid2 >> 1, mo = (tid2 & 1) << 4;
            const unsigned short* src = kglob + (size_t)d * SL + (m0 + 32) + mo;
            us8 a = *(const us8*)src;
            us8 b = *(const us8*)(src + 8);
#pragma unroll
            for (int i = 0; i < 8; ++i) { sk[cur ^ 1][mh][mo + i][d] = a[i]; sk[cur ^ 1][mh][mo + 8 + i][d] = b[i]; }
        }

        const int rb = m0 - l0w + 480;                       // rect row base (>= 0 always)
        int r1row = rb + 32 + lo; if (r1row > 1022) r1row = 1022;  // row j=63 unused; clamp OOB
        const bf16x8* ep0 = ebase + (size_t)(rb + lo) * 8;
        const bf16x8* ep1 = ebase + (size_t)r1row * 8;

        bf16x8 kf[4];
#pragma unroll
        for (int ds = 0; ds < 4; ++ds)
            kf[ds] = *(const bf16x8*)&sk[cur][mh][lo][16 * ds + 8 * hi];

        f32x16 ra = ZERO16, rc = ZERO16, sacc = ZERO16;
#pragma unroll
        for (int ds = 0; ds < 4; ++ds) {
            ra   = MFMA(ep0[2 * ds + hi], qf[ds], ra);   // rel rect rows j = 0..31
            rc   = MFMA(ep1[2 * ds + hi], qf[ds], rc);   // rel rect rows j = 32..63
            sacc = MFMA(kf[ds], qf[ds], sacc);           // S^T tile
        }
        // V fragments for this m-tile (issued early; consumed after softmax)
        const int mu = (m0 >> 3) + hi;
        bf16x8 vf00 = vb0[mu], vf01 = vb0[mu + 2];
        bf16x8 vf10 = vb1[mu], vf11 = vb1[mu + 2];

        // rect -> LDS as [l'=lo][j^sw]: 8 x ds_write_b128, conflict-free via XOR swizzle
#pragma unroll
        for (int g = 0; g < 4; ++g) {
            const int j0 = 8 * g + 4 * hi;
            f32x4 w0 = { ra[4 * g], ra[4 * g + 1], ra[4 * g + 2], ra[4 * g + 3] };
            f32x4 w1 = { rc[4 * g], rc[4 * g + 1], rc[4 * g + 2], rc[4 * g + 3] };
            *(f32x4*)(rrow + (j0 ^ sw))        = w0;
            *(f32x4*)(rrow + ((j0 + 32) ^ sw)) = w1;
        }
        // sheared gather: S[m'][l'] += rel^T[j = m'+31-l'][l']   (own-row reads, <=2-way banks)
        float s[16];
#pragma unroll
        for (int r = 0; r < 16; ++r) {
            const int mp = (r & 3) + 8 * (r >> 2) + 4 * hi;   // m' of this reg
            s[r] = sacc[r] + rrow[(mp + 31 - lo) ^ sw];
        }

        // ---- online softmax (per-lane column l'; merge hi-pair via shfl_xor 32) ----
        float tmx = s[0];
#pragma unroll
        for (int r = 1; r < 16; ++r) tmx = fmaxf(tmx, s[r]);
        tmx = fmaxf(tmx, __shfl_xor(tmx, 32, 64));
        const float nmx = fmaxf(mx, tmx);
        if (__any(nmx > mx)) {
            const float sc = __expf(mx - nmx);
#pragma unroll
            for (int r = 0; r < 16; ++r) { o0[r] *= sc; o1[r] *= sc; }
            sum *= sc;
            mx = nmx;
        }
        u32 pk[8], xk[8];
        float ps = 0.f;
#pragma unroll
        for (int q2 = 0; q2 < 8; ++q2) {
            union { __hip_bfloat162 b; u32 u; } cv;
            cv.b = __float22bfloat162_rn(make_float2(__expf(s[2 * q2] - mx),
                                                     __expf(s[2 * q2 + 1] - mx)));
            pk[q2] = cv.u;
            float2 g = __bfloat1622float2(cv.b);   // sum the *rounded* P for consistency
            ps += g.x + g.y;
        }
        sum += ps;
#pragma unroll
        for (int q2 = 0; q2 < 8; ++q2) xk[q2] = (u32)__shfl_xor((int)pk[q2], 32, 64);

        // P^T B-fragments (k = m within 16-slice; swap middle quads with hi-partner)
        union { u32 u[4]; bf16x8 v; } pf0, pf1;
        if (hi == 0) {
            pf0.u[0] = pk[0]; pf0.u[1] = pk[1]; pf0.u[2] = xk[0]; pf0.u[3] = xk[1];
            pf1.u[0] = pk[4]; pf1.u[1] = pk[5]; pf1.u[2] = xk[4]; pf1.u[3] = xk[5];
        } else {
            pf0.u[0] = xk[2]; pf0.u[1] = xk[3]; pf0.u[2] = pk[2]; pf0.u[3] = pk[3];
            pf1.u[0] = xk[6]; pf1.u[1] = xk[7]; pf1.u[2] = pk[6]; pf1.u[3] = pk[7];
        }
        o0 = MFMA(vf00, pf0.v, o0);
        o0 = MFMA(vf01, pf1.v, o0);
        o1 = MFMA(vf10, pf0.v, o1);
        o1 = MFMA(vf11, pf1.v, o1);

        __syncthreads();   // staged tile (cur^1) visible; buf cur safe to overwrite next step
    }

    // merge hi-pair partial sums (mx already identical across the pair)
    sum += __shfl_xor(sum, 32, 64);

    // ---- flash merge of the two m-halves (mh==1 publishes, mh==0 combines & stores) ----
    if (mh == 1) {
        if (hi == 0) { sstat[slab][0][lo] = mx; sstat[slab][1][lo] = sum; }
        float* ob = rect;   // reuse own rect region as [d][l'] (stride 32: conflict-free)
#pragma unroll
        for (int r = 0; r < 16; ++r) {
            const int d0 = (r & 3) + 8 * (r >> 2) + 4 * hi;
            ob[d0 * 32 + lo]        = o0[r];
            ob[(32 + d0) * 32 + lo] = o1[r];
        }
    }
    __syncthreads();
    if (mh == 0) {
        const float mx1 = sstat[slab][0][lo], s1 = sstat[slab][1][lo];
        const float nm = fmaxf(mx, mx1);
        const float a0 = __expf(mx - nm);
        const float a1 = __expf(mx1 - nm);
        const float inv = 1.f / (a0 * sum + a1 * s1);
        const float* ob = srect[wid + 2];
        unsigned short* orow = (unsigned short*)out + ((size_t)bh * SL + l0w + lo) * DH;
#pragma unroll
        for (int r = 0; r < 16; r += 2) {
            const int d0 = (r & 3) + 8 * (r >> 2) + 4 * hi;   // even; (r,r+1) -> (d0,d0+1)
            union { __hip_bfloat162 b; u32 u; } c0, c1;
            c0.b = __float22bfloat162_rn(make_float2(
                (a0 * o0[r]     + a1 * ob[d0 * 32 + lo]) * inv,
                (a0 * o0[r + 1] + a1 * ob[(d0 + 1) * 32 + lo]) * inv));
            *(u32*)(orow + d0) = c0.u;
            c1.b = __float22bfloat162_rn(make_float2(
                (a0 * o1[r]     + a1 * ob[(32 + d0) * 32 + lo]) * inv,
                (a0 * o1[r + 1] + a1 * ob[(32 + d0 + 1) * 32 + lo]) * inv));
            *(u32*)(orow + 32 + d0) = c1.u;
        }
    }
}

// ---------- fp32 fallback (MODE 1) — inert when data is bf16 ----------
template <typename T, int MODE>
__global__ __launch_bounds__(256) void attn_rel_kernel(
    const T* __restrict__ qkv, const T* __restrict__ k_emb,
    T* __restrict__ out, const int* __restrict__ flag)
{
    if (*flag != MODE) return;
    const int t = threadIdx.x;
    __shared__ float s_q[DH];
    __shared__ float s_w[SL];
    __shared__ float s_red[24];
    __shared__ float s_part[256];

    for (int it = 0; it < 16; ++it) {
        const int bid = blockIdx.x * 16 + it;
        const int l   = bid & (SL - 1);
        const int bh  = bid >> 9;
        const int h   = bh & (NH - 1);
        const long base = (long)bh * (3 * DH) * SL;

        __syncthreads();
        if (t < DH) s_q[t] = ldv(&qkv[base + (long)t * SL + l]);
        __syncthreads();

        const T* kp = qkv + base + (long)DH * SL;
        const T* ke = k_emb + (long)h * (2 * SL - 1) * DH;
        float lg[2];
#pragma unroll
        for (int i = 0; i < 2; ++i) {
            const int m = t + i * 256;
            float acc = 0.f;
#pragma unroll 8
            for (int d = 0; d < DH; ++d)
                acc += s_q[d] * ldv(&kp[(long)d * SL + m]);
            const int r = m - l + (SL - 1);
            const T* kr = ke + (long)r * DH;
            float acc2 = 0.f;
#pragma unroll 8
            for (int d = 0; d < DH; ++d)
                acc2 += s_q[d] * ldv(&kr[d]);
            lg[i] = acc + acc2;
        }

        float mxv = fmaxf(lg[0], lg[1]);
        for (int off = 32; off > 0; off >>= 1)
            mxv = fmaxf(mxv, __shfl_down(mxv, off, 64));
        if ((t & 63) == 0) s_red[t >> 6] = mxv;
        __syncthreads();
        if (t == 0)
            s_red[8] = fmaxf(fmaxf(s_red[0], s_red[1]), fmaxf(s_red[2], s_red[3]));
        __syncthreads();
        mxv = s_red[8];

        const float e0 = expf(lg[0] - mxv);
        const float e1 = expf(lg[1] - mxv);
        s_w[t] = e0;
        s_w[t + 256] = e1;
        float sm = e0 + e1;
        for (int off = 32; off > 0; off >>= 1)
            sm += __shfl_down(sm, off, 64);
        if ((t & 63) == 0) s_red[16 + (t >> 6)] = sm;
        __syncthreads();
        const float inv = 1.0f / (s_red[16] + s_red[17] + s_red[18] + s_red[19]);

        const T* vp = qkv + base + (long)(2 * DH) * SL;
        const int g  = t >> 6;
        const int dd = t & 63;
        const T* vrow = vp + (long)dd * SL + g * 128;
        const float* wrow = s_w + g * 128;
        float acc = 0.f;
#pragma unroll 8
        for (int m = 0; m < 128; ++m)
            acc += wrow[m] * ldv(&vrow[m]);
        s_part[t] = acc;
        __syncthreads();
        if (t < 64) {
            float o = (s_part[t] + s_part[t + 64] + s_part[t + 128] + s_part[t + 192]) * inv;
            stv(&out[((long)bh * SL + l) * DH + t], o);
        }
    }
}

extern "C" void kernel_launch(void* const* d_in, const int* in_sizes, int n_in,
                              void* d_out, int out_size, void* d_ws, size_t ws_size,
                              hipStream_t stream) {
    (void)in_sizes; (void)n_in; (void)out_size; (void)ws_size;
    int* flag = (int*)d_ws;

    detect_dtype_kernel<<<1, 256, 0, stream>>>((const unsigned short*)d_in[0], flag);

    // bf16 flash path (MODE 0) — no workspace needed beyond the flag
    attn_flash_bf16<<<512, 256, 0, stream>>>(
        (const __hip_bfloat16*)d_in[0], (const __hip_bfloat16*)d_in[1],
        (__hip_bfloat16*)d_out, flag);

    // fp32 interpretation (MODE 1) — self-disables via flag when data is bf16
    attn_rel_kernel<float, 1><<<2048, 256, 0, stream>>>(
        (const float*)d_in[0], (const float*)d_in[1], (float*)d_out, flag);
}

// Round 3
// 128.007 us; speedup vs baseline: 11.6357x; 11.6232x over previous
//
#include <hip/hip_runtime.h>
#include <hip/hip_bf16.h>

#define NH 8
#define DH 64
#define SL 512

typedef __bf16 bf16x8 __attribute__((ext_vector_type(8)));
typedef float f32x16 __attribute__((ext_vector_type(16)));
typedef float f32x4 __attribute__((ext_vector_type(4)));
typedef unsigned int u32;

#define MFMA(a, b, c) __builtin_amdgcn_mfma_f32_32x32x16_bf16(a, b, c, 0, 0, 0)
#define ZERO16 {0.f,0.f,0.f,0.f,0.f,0.f,0.f,0.f,0.f,0.f,0.f,0.f,0.f,0.f,0.f,0.f}

union BF8 { unsigned short s[8]; bf16x8 v; };

__device__ __forceinline__ unsigned short f2bf(float x) {   // RN-even fp32->bf16
    union { float f; u32 u; } v; v.f = x;
    return (unsigned short)((v.u + 0x7fffu + ((v.u >> 16) & 1u)) >> 16);
}
__device__ __forceinline__ float bf2f(unsigned short s) {
    union { u32 u; float f; } v; v.u = ((u32)s) << 16; return v.f;
}
// load 8 consecutive fp32, split into hi/lo bf16x8 fragments
__device__ __forceinline__ void loadsplit8(const float* p, bf16x8& h8, bf16x8& l8) {
    f32x4 a = *(const f32x4*)p;
    f32x4 b = *(const f32x4*)(p + 4);
    BF8 uh, ul;
#pragma unroll
    for (int i = 0; i < 4; ++i) {
        unsigned short h0 = f2bf(a[i]); uh.s[i]     = h0; ul.s[i]     = f2bf(a[i] - bf2f(h0));
        unsigned short h1 = f2bf(b[i]); uh.s[4 + i] = h1; ul.s[4 + i] = f2bf(b[i] - bf2f(h1));
    }
    h8 = uh.v; l8 = ul.v;
}

// ---------- dtype-detect: is the input buffer bf16 or fp32? ----------
__global__ void detect_dtype_kernel(const unsigned short* __restrict__ q, int* __restrict__ flag) {
    int t = threadIdx.x;
    unsigned int u = (unsigned int)q[t];
    float f = __uint_as_float(u << 16);
    bool big = !(fabsf(f) <= 1e4f);   // true for huge OR NaN
    unsigned long long vote = __ballot(big);
    __shared__ int any;
    if (t == 0) any = 0;
    __syncthreads();
    if (vote != 0ull && (t & 63) == 0) atomicOr(&any, 1);
    __syncthreads();
    if (t == 0) *flag = any;          // 1 => fp32 data, 0 => bf16 data
}

// ---------- load/store helpers (fallback path) ----------
__device__ __forceinline__ float ldv(const __hip_bfloat16* p) { return __bfloat162float(*p); }
__device__ __forceinline__ float ldv(const float* p) { return *p; }
__device__ __forceinline__ void stv(__hip_bfloat16* p, float v) { *p = __float2bfloat16(v); }
__device__ __forceinline__ void stv(float* p, float v) { *p = v; }

// ---------- fused flash attention w/ relative logits, FP32 inputs via split-bf16 MFMA (MODE 1) ----------
// One block per (bh, 64-row l-tile). 4 waves: (slab = wid&1 [32 l-rows], mh = wid>>1 [256-m half]).
// S^T = Khi*Qhi + Khi*Qlo + Klo*Qhi (mfma, ~16 mantissa bits); rel = Ehi*Qhi sheared via LDS;
// O^T = (Vhi+Vlo)*P^T with P in bf16 (sum over rounded P for consistent normalization).
__global__ __launch_bounds__(256, 2) void attn_flash_f32(
    const float* __restrict__ qkv,      // [bh][3*64][512]
    const float* __restrict__ k_emb,    // [H][1023][64]
    float* __restrict__ out,            // [bh][512][64] raw
    const int* __restrict__ flag)
{
    if (*flag != 1) return;
    const int bid = blockIdx.x;
    // XCD swizzle: XCD c gets bh in [8c,8c+8) entirely (K/V/k_emb L2-resident per XCD)
    const int swz = (bid & 7) * 64 + (bid >> 3);
    const int bh = swz >> 3, lt = swz & 7;
    const int h  = bh & (NH - 1);
    const int t = threadIdx.x;
    const int wid = t >> 6, lane = t & 63;
    const int lo = lane & 31, hi = lane >> 5;
    const int slab = wid & 1, mh = wid >> 1;
    const int l0w = lt * 64 + slab * 32;

    // LDS: [0,9216) Khi [2][32][72]us | [9216,18432) Klo | [18432,51200) rect 4x2048 f32
    //      (Q hi/lo tiles overlay the rect region during init) | [51200,51712) stats
    __shared__ __align__(16) unsigned char smem[51712];
    unsigned short (*skh)[32][72] = (unsigned short (*)[32][72])(smem);
    unsigned short (*skl)[32][72] = (unsigned short (*)[32][72])(smem + 9216);
    float* rect = (float*)(smem + 18432) + wid * 2048;
    unsigned short (*sqh)[72] = (unsigned short (*)[72])(smem + 18432);
    unsigned short (*sql)[72] = (unsigned short (*)[72])(smem + 18432 + 9216);
    float* sstat = (float*)(smem + 18432 + 32768);   // [slab*64 + {0..31 mx | 32..63 sum}]

    const float* qbase = qkv + (size_t)bh * (3 * DH * SL);
    const float* kglob = qbase + DH * SL;
    const float* vflat = qbase + (size_t)2 * DH * SL;
    const float* ebase = k_emb + (size_t)h * (2 * SL - 1) * DH;

    // ---- stage Q tile (fp32 [d][l] -> hi/lo bf16 [l][d]) ----
    {
        const int d = t >> 2, c = (t & 3) * 16;
        const float* src = qbase + (size_t)d * SL + lt * 64 + c;
#pragma unroll
        for (int g = 0; g < 4; ++g) {
            f32x4 x = *(const f32x4*)(src + 4 * g);
#pragma unroll
            for (int i = 0; i < 4; ++i) {
                unsigned short hb = f2bf(x[i]);
                sqh[c + 4 * g + i][d] = hb;
                sql[c + 4 * g + i][d] = f2bf(x[i] - bf2f(hb));
            }
        }
    }
    // ---- stage K tile for step 0 (each mh-pair stages its own [32m][64d] tile) ----
    {
        const int tid2 = slab * 64 + lane;          // 0..127 within mh-pair
        const int d = tid2 >> 1, mo = (tid2 & 1) << 4;
        const float* src = kglob + (size_t)d * SL + mh * 256 + mo;
#pragma unroll
        for (int g = 0; g < 4; ++g) {
            f32x4 x = *(const f32x4*)(src + 4 * g);
#pragma unroll
            for (int i = 0; i < 4; ++i) {
                unsigned short hb = f2bf(x[i]);
                skh[mh][mo + 4 * g + i][d] = hb;
                skl[mh][mo + 4 * g + i][d] = f2bf(x[i] - bf2f(hb));
            }
        }
    }
    __syncthreads();

    // Q fragments (held in regs for the whole m-loop)
    bf16x8 qfh[4], qfl[4];
#pragma unroll
    for (int ds = 0; ds < 4; ++ds) {
        qfh[ds] = *(const bf16x8*)&sqh[slab * 32 + lo][16 * ds + 8 * hi];
        qfl[ds] = *(const bf16x8*)&sql[slab * 32 + lo][16 * ds + 8 * hi];
    }
    __syncthreads();   // everyone done reading sq -> rect region free

    const int sw = (lo & 7) << 2;   // XOR col-swizzle: conflict-free rect access
    float* rrow = rect + lo * 64;

    f32x16 o0 = ZERO16, o1 = ZERO16;      // O^T accum: d 0-31 / 32-63, col l' = lo
    float mx = -1e30f, sum = 0.f;

    for (int step = 0; step < 8; ++step) {
        const int m0 = mh * 256 + step * 32;
        const int rb = m0 - l0w + 480;                       // rect row base (always >= 0)

        // ---- E fragments (k_emb, hi only), direct from global ----
        int r1 = rb + 32 + lo; if (r1 > 1022) r1 = 1022;     // row j=63 unused; clamp OOB
        const float* e0p = ebase + (size_t)(rb + lo) * DH;
        const float* e1p = ebase + (size_t)r1 * DH;
        bf16x8 ea[4], ec[4];
#pragma unroll
        for (int ds = 0; ds < 4; ++ds) {
            const int off = 16 * ds + 8 * hi;
            f32x4 a0 = *(const f32x4*)(e0p + off);
            f32x4 a1 = *(const f32x4*)(e0p + off + 4);
            f32x4 c0 = *(const f32x4*)(e1p + off);
            f32x4 c1 = *(const f32x4*)(e1p + off + 4);
            BF8 ua, uc;
#pragma unroll
            for (int i = 0; i < 4; ++i) {
                ua.s[i] = f2bf(a0[i]); ua.s[4 + i] = f2bf(a1[i]);
                uc.s[i] = f2bf(c0[i]); uc.s[4 + i] = f2bf(c1[i]);
            }
            ea[ds] = ua.v; ec[ds] = uc.v;
        }
        // ---- V fragments hi/lo (native [d][m] fp32 rows) ----
        const float* v0p = vflat + (size_t)lo * SL + m0 + 8 * hi;
        const float* v1p = vflat + (size_t)(32 + lo) * SL + m0 + 8 * hi;
        bf16x8 v00h, v00l, v01h, v01l, v10h, v10l, v11h, v11l;
        loadsplit8(v0p,      v00h, v00l);
        loadsplit8(v0p + 16, v01h, v01l);
        loadsplit8(v1p,      v10h, v10l);
        loadsplit8(v1p + 16, v11h, v11l);

        // ---- MFMA block: S^T (split product) + rel rect ----
        f32x16 ra = ZERO16, rc = ZERO16, sacc = ZERO16;
#pragma unroll
        for (int ds = 0; ds < 4; ++ds) {
            bf16x8 kh = *(const bf16x8*)&skh[mh][lo][16 * ds + 8 * hi];
            bf16x8 kl = *(const bf16x8*)&skl[mh][lo][16 * ds + 8 * hi];
            sacc = MFMA(kh, qfh[ds], sacc);
            sacc = MFMA(kh, qfl[ds], sacc);
            sacc = MFMA(kl, qfh[ds], sacc);
            ra   = MFMA(ea[ds], qfh[ds], ra);    // rel rows j = 0..31
            rc   = MFMA(ec[ds], qfh[ds], rc);    // rel rows j = 32..63
        }

        // rect -> LDS [l'][j^sw] (8 x b128, conflict-free), sheared gather back
#pragma unroll
        for (int g = 0; g < 4; ++g) {
            const int j0 = 8 * g + 4 * hi;
            f32x4 w0 = { ra[4 * g], ra[4 * g + 1], ra[4 * g + 2], ra[4 * g + 3] };
            f32x4 w1 = { rc[4 * g], rc[4 * g + 1], rc[4 * g + 2], rc[4 * g + 3] };
            *(f32x4*)(rrow + (j0 ^ sw))        = w0;
            *(f32x4*)(rrow + ((j0 + 32) ^ sw)) = w1;
        }
        float s[16];
#pragma unroll
        for (int r = 0; r < 16; ++r) {
            const int mp = (r & 3) + 8 * (r >> 2) + 4 * hi;   // m' of this reg
            s[r] = sacc[r] + rrow[(mp + 31 - lo) ^ sw];       // + rel^T[j=m'+31-l'][l']
        }

        // ---- online softmax (per-lane col l'; hi-pair merged via shfl_xor 32) ----
        float tmx = s[0];
#pragma unroll
        for (int r = 1; r < 16; ++r) tmx = fmaxf(tmx, s[r]);
        tmx = fmaxf(tmx, __shfl_xor(tmx, 32, 64));
        const float nmx = fmaxf(mx, tmx);
        if (__any(nmx > mx)) {
            const float sc = __expf(mx - nmx);
#pragma unroll
            for (int r = 0; r < 16; ++r) { o0[r] *= sc; o1[r] *= sc; }
            sum *= sc;
            mx = nmx;
        }
        u32 pk[8], xk[8];
        float ps = 0.f;
#pragma unroll
        for (int q2 = 0; q2 < 8; ++q2) {
            union { __hip_bfloat162 b; u32 u; } cv;
            cv.b = __float22bfloat162_rn(make_float2(__expf(s[2 * q2] - mx),
                                                     __expf(s[2 * q2 + 1] - mx)));
            pk[q2] = cv.u;
            float2 g2 = __bfloat1622float2(cv.b);   // sum the *rounded* P for consistency
            ps += g2.x + g2.y;
        }
        sum += ps;
#pragma unroll
        for (int q2 = 0; q2 < 8; ++q2) xk[q2] = (u32)__shfl_xor((int)pk[q2], 32, 64);

        // P^T B-fragments (k = m within 16-slice; swap middle quads with hi-partner)
        union { u32 u[4]; bf16x8 v; } pf0, pf1;
        if (hi == 0) {
            pf0.u[0] = pk[0]; pf0.u[1] = pk[1]; pf0.u[2] = xk[0]; pf0.u[3] = xk[1];
            pf1.u[0] = pk[4]; pf1.u[1] = pk[5]; pf1.u[2] = xk[4]; pf1.u[3] = xk[5];
        } else {
            pf0.u[0] = xk[2]; pf0.u[1] = xk[3]; pf0.u[2] = pk[2]; pf0.u[3] = pk[3];
            pf1.u[0] = xk[6]; pf1.u[1] = xk[7]; pf1.u[2] = pk[6]; pf1.u[3] = pk[7];
        }
        o0 = MFMA(v00h, pf0.v, o0);
        o0 = MFMA(v00l, pf0.v, o0);
        o0 = MFMA(v01h, pf1.v, o0);
        o0 = MFMA(v01l, pf1.v, o0);
        o1 = MFMA(v10h, pf0.v, o1);
        o1 = MFMA(v10l, pf0.v, o1);
        o1 = MFMA(v11h, pf1.v, o1);
        o1 = MFMA(v11l, pf1.v, o1);

        // ---- single-buffered K restage for next step ----
        if (step < 7) {
            __syncthreads();   // all waves done reading K[step]
            const int m0n = mh * 256 + (step + 1) * 32;
            const int tid2 = slab * 64 + lane;
            const int d = tid2 >> 1, mo = (tid2 & 1) << 4;
            const float* src = kglob + (size_t)d * SL + m0n + mo;
#pragma unroll
            for (int g = 0; g < 4; ++g) {
                f32x4 x = *(const f32x4*)(src + 4 * g);
#pragma unroll
                for (int i = 0; i < 4; ++i) {
                    unsigned short hb = f2bf(x[i]);
                    skh[mh][mo + 4 * g + i][d] = hb;
                    skl[mh][mo + 4 * g + i][d] = f2bf(x[i] - bf2f(hb));
                }
            }
            __syncthreads();   // K[step+1] visible
        }
    }

    // merge hi-pair partial sums (mx already identical across the pair)
    sum += __shfl_xor(sum, 32, 64);

    // ---- flash merge of the two m-halves (mh==1 publishes, mh==0 combines & stores) ----
    if (mh == 1) {
        if (hi == 0) { sstat[slab * 64 + lo] = mx; sstat[slab * 64 + 32 + lo] = sum; }
        float* ob = rect;   // reuse own rect region as [d][l'] (stride 32, conflict-free)
#pragma unroll
        for (int r = 0; r < 16; ++r) {
            const int d0 = (r & 3) + 8 * (r >> 2) + 4 * hi;
            ob[d0 * 32 + lo]        = o0[r];
            ob[(32 + d0) * 32 + lo] = o1[r];
        }
    }
    __syncthreads();
    if (mh == 0) {
        const float mx1 = sstat[slab * 64 + lo], s1 = sstat[slab * 64 + 32 + lo];
        const float nm = fmaxf(mx, mx1);
        const float a0 = __expf(mx - nm);
        const float a1 = __expf(mx1 - nm);
        const float inv = 1.f / (a0 * sum + a1 * s1);
        const float* ob = (float*)(smem + 18432) + (wid + 2) * 2048;
        float* orow = out + ((size_t)bh * SL + l0w + lo) * DH;
#pragma unroll
        for (int r = 0; r < 16; r += 2) {
            const int d0 = (r & 3) + 8 * (r >> 2) + 4 * hi;   // even; (r,r+1)->(d0,d0+1)
            float2 w0 = make_float2((a0 * o0[r]     + a1 * ob[d0 * 32 + lo]) * inv,
                                    (a0 * o0[r + 1] + a1 * ob[(d0 + 1) * 32 + lo]) * inv);
            *(float2*)(orow + d0) = w0;
            float2 w1 = make_float2((a0 * o1[r]     + a1 * ob[(32 + d0) * 32 + lo]) * inv,
                                    (a0 * o1[r + 1] + a1 * ob[(32 + d0 + 1) * 32 + lo]) * inv);
            *(float2*)(orow + 32 + d0) = w1;
        }
    }
}

// ---------- scalar fallback (bf16 MODE 0) — inert when data is fp32 ----------
template <typename T, int MODE>
__global__ __launch_bounds__(256) void attn_rel_kernel(
    const T* __restrict__ qkv, const T* __restrict__ k_emb,
    T* __restrict__ out, const int* __restrict__ flag)
{
    if (*flag != MODE) return;
    const int t = threadIdx.x;
    __shared__ float s_q[DH];
    __shared__ float s_w[SL];
    __shared__ float s_red[24];
    __shared__ float s_part[256];

    for (int it = 0; it < 16; ++it) {
        const int bid = blockIdx.x * 16 + it;
        const int l   = bid & (SL - 1);
        const int bh  = bid >> 9;
        const int h   = bh & (NH - 1);
        const long base = (long)bh * (3 * DH) * SL;

        __syncthreads();
        if (t < DH) s_q[t] = ldv(&qkv[base + (long)t * SL + l]);
        __syncthreads();

        const T* kp = qkv + base + (long)DH * SL;
        const T* ke = k_emb + (long)h * (2 * SL - 1) * DH;
        float lg[2];
#pragma unroll
        for (int i = 0; i < 2; ++i) {
            const int m = t + i * 256;
            float acc = 0.f;
#pragma unroll 8
            for (int d = 0; d < DH; ++d)
                acc += s_q[d] * ldv(&kp[(long)d * SL + m]);
            const int r = m - l + (SL - 1);
            const T* kr = ke + (long)r * DH;
            float acc2 = 0.f;
#pragma unroll 8
            for (int d = 0; d < DH; ++d)
                acc2 += s_q[d] * ldv(&kr[d]);
            lg[i] = acc + acc2;
        }

        float mxv = fmaxf(lg[0], lg[1]);
        for (int off = 32; off > 0; off >>= 1)
            mxv = fmaxf(mxv, __shfl_down(mxv, off, 64));
        if ((t & 63) == 0) s_red[t >> 6] = mxv;
        __syncthreads();
        if (t == 0)
            s_red[8] = fmaxf(fmaxf(s_red[0], s_red[1]), fmaxf(s_red[2], s_red[3]));
        __syncthreads();
        mxv = s_red[8];

        const float e0 = expf(lg[0] - mxv);
        const float e1 = expf(lg[1] - mxv);
        s_w[t] = e0;
        s_w[t + 256] = e1;
        float sm = e0 + e1;
        for (int off = 32; off > 0; off >>= 1)
            sm += __shfl_down(sm, off, 64);
        if ((t & 63) == 0) s_red[16 + (t >> 6)] = sm;
        __syncthreads();
        const float inv = 1.0f / (s_red[16] + s_red[17] + s_red[18] + s_red[19]);

        const T* vp = qkv + base + (long)(2 * DH) * SL;
        const int g  = t >> 6;
        const int dd = t & 63;
        const T* vrow = vp + (long)dd * SL + g * 128;
        const float* wrow = s_w + g * 128;
        float acc = 0.f;
#pragma unroll 8
        for (int m = 0; m < 128; ++m)
            acc += wrow[m] * ldv(&vrow[m]);
        s_part[t] = acc;
        __syncthreads();
        if (t < 64) {
            float o = (s_part[t] + s_part[t + 64] + s_part[t + 128] + s_part[t + 192]) * inv;
            stv(&out[((long)bh * SL + l) * DH + t], o);
        }
    }
}

extern "C" void kernel_launch(void* const* d_in, const int* in_sizes, int n_in,
                              void* d_out, int out_size, void* d_ws, size_t ws_size,
                              hipStream_t stream) {
    (void)in_sizes; (void)n_in; (void)out_size; (void)ws_size;
    int* flag = (int*)d_ws;

    detect_dtype_kernel<<<1, 256, 0, stream>>>((const unsigned short*)d_in[0], flag);

    // fp32 flash path (MODE 1) — the real path for this harness
    attn_flash_f32<<<512, 256, 0, stream>>>(
        (const float*)d_in[0], (const float*)d_in[1], (float*)d_out, flag);

    // bf16 scalar fallback (MODE 0) — self-disables via flag when data is fp32
    attn_rel_kernel<__hip_bfloat16, 0><<<2048, 256, 0, stream>>>(
        (const __hip_bfloat16*)d_in[0], (const __hip_bfloat16*)d_in[1],
        (__hip_bfloat16*)d_out, flag);
}